// Round 11
// baseline (1745.958 us; speedup 1.0000x reference)
//
#include <hip/hip_runtime.h>
#include <math.h>

#define EPS 1e-8f

constexpr int N_USERS = 6000;
constexpr int N_ITEMS = 4000;
constexpr int NU_P = 6016;  // 47 * 128
constexpr int NI_P = 4096;  // 32 * 128
constexpr int CMP_W = 192;  // max degree per item row (out 20 + in ~Poi(20))

typedef __bf16 bf16_8 __attribute__((ext_vector_type(8)));
typedef float f32_4 __attribute__((ext_vector_type(4)));
typedef int i32x4 __attribute__((ext_vector_type(4)));

// ---------------------------------------------------------------------------
__device__ __forceinline__ void stage16(const void* g, void* l) {
  __builtin_amdgcn_global_load_lds(
      (const __attribute__((address_space(1))) void*)g,
      (__attribute__((address_space(3))) void*)l, 16, 0, 0);
}

// XCD-aware bijective swizzle (requires nwg % 8 == 0; all MFMA grids are).
__device__ __forceinline__ int xcd_swz(int p, int nwg) {
  return (p & 7) * (nwg >> 3) + (p >> 3);
}

// triangular decode: p -> (by, bx) with bx <= by
__device__ __forceinline__ void tri_decode(int p, int& by, int& bx) {
  int r = (int)((sqrtf(8.f * p + 1.f) - 1.f) * 0.5f);
  while ((r + 1) * (r + 2) / 2 <= p) r++;
  while (r * (r + 1) / 2 > p) r--;
  by = r;
  bx = p - r * (r + 1) / 2;
}

// grouped decode (G=8 rows, column-major within band) for L2 locality
__device__ __forceinline__ void grp_decode(int p, int nby, int nbx, int& by,
                                           int& bx) {
  const int G = 8;
  const int wide = G * nbx;
  const int band = p / wide;
  const int rem = p - band * wide;
  const int h = min(G, nby - band * G);
  by = band * G + rem % h;
  bx = rem / h;
}

// ---------------------------------------------------------------------------
// bf16 prop GEMM — ROUND-7 KERNEL VERBATIM (measured 376-380 us; empirical
// optimum of the 128^2 structure). Used for prop2 only now.
// ---------------------------------------------------------------------------
template <int KK, int LDA, int LDB, int LDC, int OUTBF16>
__global__ __launch_bounds__(256) void mfma_prop_bf16(
    const __bf16* __restrict__ A, const __bf16* __restrict__ B,
    float* __restrict__ Cf, __bf16* __restrict__ Cb, int M, int N, int nby,
    int nbx) {
  __shared__ __bf16 sA[2][128 * 32];
  __shared__ __bf16 sB[2][128 * 32];

  int by, bx;
  grp_decode(xcd_swz(blockIdx.x, gridDim.x), nby, nbx, by, bx);

  const int tid = threadIdx.x;
  const int lane = tid & 63;
  const int wave = tid >> 6;
  const int wm = (wave >> 1) * 64;
  const int wn = (wave & 1) * 64;
  const int lm = lane & 15;
  const int kg = lane >> 4;
  const long row0 = (long)by * 128;
  const long col0 = (long)bx * 128;

  f32_4 acc[4][4];
#pragma unroll
  for (int i = 0; i < 4; i++)
#pragma unroll
    for (int j = 0; j < 4; j++) acc[i][j] = (f32_4){0.f, 0.f, 0.f, 0.f};

  const int c0 = tid, c1 = tid + 256;
  const int r0c = c0 >> 2, j0c = ((c0 & 3) - (r0c >> 1)) & 3;
  const int r1c = c1 >> 2, j1c = ((c1 & 3) - (r1c >> 1)) & 3;

  // loop-invariant fragment offsets (elements)
  int offA[4], offB[4];
#pragma unroll
  for (int i = 0; i < 4; i++) {
    const int ra = wm + i * 16 + lm;
    const int rb = wn + i * 16 + lm;
    offA[i] = (ra * 4 + ((kg + (ra >> 1)) & 3)) * 8;
    offB[i] = (rb * 4 + ((kg + (rb >> 1)) & 3)) * 8;
  }

  const __bf16* a0 = A + (row0 + r0c) * LDA + j0c * 8;
  const __bf16* a1 = A + (row0 + r1c) * LDA + j1c * 8;
  const __bf16* b0 = B + (col0 + r0c) * LDB + j0c * 8;
  const __bf16* b1 = B + (col0 + r1c) * LDB + j1c * 8;

  for (int k0 = 0; k0 < KK; k0 += 64) {
    stage16(a0 + k0, &sA[0][c0 * 8]);
    stage16(a1 + k0, &sA[0][c1 * 8]);
    stage16(b0 + k0, &sB[0][c0 * 8]);
    stage16(b1 + k0, &sB[0][c1 * 8]);
    stage16(a0 + k0 + 32, &sA[1][c0 * 8]);
    stage16(a1 + k0 + 32, &sA[1][c1 * 8]);
    stage16(b0 + k0 + 32, &sB[1][c0 * 8]);
    stage16(b1 + k0 + 32, &sB[1][c1 * 8]);
    __syncthreads();

#pragma unroll
    for (int h = 0; h < 2; h++) {
      bf16_8 a[4], b[4];
#pragma unroll
      for (int i = 0; i < 4; i++) {
        a[i] = *(const bf16_8*)&sA[h][offA[i]];
        b[i] = *(const bf16_8*)&sB[h][offB[i]];
      }
#pragma unroll
      for (int i = 0; i < 4; i++)
#pragma unroll
        for (int j = 0; j < 4; j++)
          acc[i][j] = __builtin_amdgcn_mfma_f32_16x16x32_bf16(a[i], b[j],
                                                              acc[i][j], 0, 0,
                                                              0);
    }
    __syncthreads();
  }

  // epilogue: C/D layout col=lane&15, row=(lane>>4)*4+reg
#pragma unroll
  for (int i = 0; i < 4; i++)
#pragma unroll
    for (int j = 0; j < 4; j++)
#pragma unroll
      for (int r = 0; r < 4; r++) {
        const long gm = row0 + wm + i * 16 + kg * 4 + r;
        const long gn = col0 + wn + j * 16 + lm;
        if (gm < M && gn < N) {
          if (OUTBF16)
            Cb[gm * LDC + gn] = (__bf16)acc[i][j][r];
          else
            Cf[gm * LDC + gn] = acc[i][j][r];
        }
      }
}

// ---------------------------------------------------------------------------
// Single-plane centered-i8 GRAM — ROUND-6 SCHEDULE + compile-time strides
// (the verified r10 kernel, byte-identical).
// ---------------------------------------------------------------------------
template <int KK, int LD, int LDC>
__global__ __launch_bounds__(256) void mfma_gram_i8(
    const signed char* __restrict__ Q, const float* __restrict__ sv,
    float* __restrict__ C, int Nn, float negq) {
  __shared__ signed char sA[128 * 64];
  __shared__ signed char sB[128 * 64];

  int by, bx;
  tri_decode(xcd_swz(blockIdx.x, gridDim.x), by, bx);

  const int tid = threadIdx.x;
  const int lane = tid & 63;
  const int wave = tid >> 6;
  const int wm = (wave >> 1) * 64;
  const int wn = (wave & 1) * 64;
  const int lm = lane & 15;
  const int kg = lane >> 4;
  const long row0 = (long)by * 128;
  const long col0 = (long)bx * 128;
  const float scale = 1.f / (254.f * 254.f);

  i32x4 acc[4][4];
#pragma unroll
  for (int i = 0; i < 4; i++)
#pragma unroll
    for (int j = 0; j < 4; j++) acc[i][j] = (i32x4){0, 0, 0, 0};

  const int c0 = tid, c1 = tid + 256;
  const int r0c = c0 >> 2, j0c = ((c0 & 3) - (r0c >> 1)) & 3;
  const int r1c = c1 >> 2, j1c = ((c1 & 3) - (r1c >> 1)) & 3;

  int offA[4], offB[4];
#pragma unroll
  for (int i = 0; i < 4; i++) {
    const int ra = wm + i * 16 + lm;
    const int rb = wn + i * 16 + lm;
    offA[i] = (ra * 4 + ((kg + (ra >> 1)) & 3)) * 16;
    offB[i] = (rb * 4 + ((kg + (rb >> 1)) & 3)) * 16;
  }

  const signed char* a0 = Q + (row0 + r0c) * LD + j0c * 16;
  const signed char* a1 = Q + (row0 + r1c) * LD + j1c * 16;
  const signed char* b0 = Q + (col0 + r0c) * LD + j0c * 16;
  const signed char* b1 = Q + (col0 + r1c) * LD + j1c * 16;

  for (int k0 = 0; k0 < KK; k0 += 64) {
    stage16(a0 + k0, &sA[c0 * 16]);
    stage16(a1 + k0, &sA[c1 * 16]);
    stage16(b0 + k0, &sB[c0 * 16]);
    stage16(b1 + k0, &sB[c1 * 16]);
    __syncthreads();

    i32x4 a[4], b[4];
#pragma unroll
    for (int i = 0; i < 4; i++) {
      a[i] = *(const i32x4*)&sA[offA[i]];
      b[i] = *(const i32x4*)&sB[offB[i]];
    }
#pragma unroll
    for (int i = 0; i < 4; i++)
#pragma unroll
      for (int j = 0; j < 4; j++)
        acc[i][j] = __builtin_amdgcn_mfma_i32_16x16x64_i8(a[i], b[j],
                                                          acc[i][j], 0, 0, 0);
    __syncthreads();
  }

#pragma unroll
  for (int i = 0; i < 4; i++)
#pragma unroll
    for (int j = 0; j < 4; j++)
#pragma unroll
      for (int r = 0; r < 4; r++) {
        const long gm = row0 + wm + i * 16 + kg * 4 + r;
        const long gn = col0 + wn + j * 16 + lm;
        if (gm < Nn && gn < Nn)
          C[gm * LDC + gn] = fmaf((float)acc[i][j][r], scale,
                                  0.5f * (sv[gm] + sv[gn]) + negq);
      }
}

// ---------------------------------------------------------------------------
// Compact one adjacency row into fixed-width (col,val) pairs + row weight sum.
// Entries are strictly positive (cosine sims of nonneg vectors, scaled), so
// !=0 detects the sparsity pattern. Order within a row is arbitrary (only
// summed downstream). One block per row.
// ---------------------------------------------------------------------------
__global__ __launch_bounds__(256) void compact_adj_kernel(
    const __bf16* __restrict__ adj, unsigned int* __restrict__ lists,
    int* __restrict__ cnts, float* __restrict__ rsw, int n, int np) {
  __shared__ int cnt;
  __shared__ float sum;
  const int i = blockIdx.x;
  if (threadIdx.x == 0) {
    cnt = 0;
    sum = 0.f;
  }
  __syncthreads();
  float my = 0.f;
  for (int j = threadIdx.x; j < n; j += 256) {
    const __bf16 a = adj[(long)i * np + j];
    const float av = (float)a;
    if (av != 0.f) {
      const int slot = atomicAdd(&cnt, 1);
      if (slot < CMP_W) {
        const unsigned short bits = *(const unsigned short*)&a;
        lists[(long)i * CMP_W + slot] =
            ((unsigned int)bits << 16) | (unsigned int)j;
      }
      my += av;
    }
  }
  atomicAdd(&sum, my);
  __syncthreads();
  if (threadIdx.x == 0) {
    cnts[i] = min(cnt, CMP_W);
    rsw[i] = sum;
  }
}

// ---------------------------------------------------------------------------
// Sparse prop1: Tt[i, u] = sum_{j in nbr(i)} w_ij * R[u, j], gathering rows
// of the centered-i8 transposed plane Qt = IhT (25 MB, L3-resident):
//   R[u,j] = q/254 + 0.5  =>  Tt[i,:] = (sum w*q)/254 + 0.5 * rsw[i].
// One block (256 threads) per item row; thread t owns columns 4t+1024s
// (s<6), char4 coalesced loads, fp32 register accumulators, bf16x4 stores.
// Pad cols of Tt get 0.5*rsw (harmless: adjU pad cols are zero in prop2).
// ---------------------------------------------------------------------------
__global__ __launch_bounds__(256) void spmm_prop1_kernel(
    const unsigned int* __restrict__ lists, const int* __restrict__ cnts,
    const float* __restrict__ rsw, const signed char* __restrict__ Qt,
    __bf16* __restrict__ Tt) {
  __shared__ unsigned int L[CMP_W];
  __shared__ int scnt;
  __shared__ float srs;
  const int i = blockIdx.x;
  const int t = threadIdx.x;
  if (t == 0) {
    scnt = cnts[i];
    srs = rsw[i];
  }
  if (t < CMP_W) L[t] = lists[(long)i * CMP_W + t];
  __syncthreads();
  const int cnt = scnt;

  float acc[6][4];
#pragma unroll
  for (int s = 0; s < 6; s++)
#pragma unroll
    for (int q = 0; q < 4; q++) acc[s][q] = 0.f;

  for (int e = 0; e < cnt; e++) {
    const unsigned int pk = L[e];
    const unsigned short wb = (unsigned short)(pk >> 16);
    const float w = (float)(*(const __bf16*)&wb);
    const long jrow = (long)(pk & 0xffffu) * NU_P;
#pragma unroll
    for (int s = 0; s < 6; s++) {
      const int u0 = 4 * t + 1024 * s;
      if (u0 < NU_P) {
        const char4 q4 = *(const char4*)&Qt[jrow + u0];
        acc[s][0] = fmaf(w, (float)q4.x, acc[s][0]);
        acc[s][1] = fmaf(w, (float)q4.y, acc[s][1]);
        acc[s][2] = fmaf(w, (float)q4.z, acc[s][2]);
        acc[s][3] = fmaf(w, (float)q4.w, acc[s][3]);
      }
    }
  }

  const float base = 0.5f * srs;
  const long orow = (long)i * NU_P;
#pragma unroll
  for (int s = 0; s < 6; s++) {
    const int u0 = 4 * t + 1024 * s;
    if (u0 < NU_P) {
      __bf16 o4[4];
#pragma unroll
      for (int q = 0; q < 4; q++)
        o4[q] = (__bf16)fmaf(acc[s][q], 1.f / 254.f, base);
      *(uint2*)&Tt[orow + u0] = *(const uint2*)&o4[0];
    }
  }
}

// ---------------------------------------------------------------------------
// R [M,N] fp32 -> padded centered-i8 plane (user gram). bf16 plane dropped
// (dense prop1 deleted; sparse prop1 gathers from IhT instead).
// ---------------------------------------------------------------------------
__global__ __launch_bounds__(256) void pad_quant_kernel(
    const float* __restrict__ R, signed char* __restrict__ Qp, int M, int N,
    int Np) {
  const int r = blockIdx.y;
  const int c = blockIdx.x * 256 + threadIdx.x;
  if (c >= Np) return;
  const bool in = (r < M && c < N);
  const float v = in ? R[(long)r * N + c] : 0.f;
  Qp[(long)r * Np + c] =
      in ? (signed char)__float2int_rn((v - 0.5f) * 254.f) : (signed char)0;
}

// ---------------------------------------------------------------------------
// Transpose fp32 [M,N] -> padded centered-i8 [Np, Mp] (item gram + spmm).
// ---------------------------------------------------------------------------
__global__ __launch_bounds__(256) void transpose_quant_kernel(
    const float* __restrict__ R, signed char* __restrict__ Qp, int M, int N,
    int Mp, int Np) {
  __shared__ float tile[32][33];
  const int tx = threadIdx.x & 31;
  const int ty = threadIdx.x >> 5;
  const int ri = blockIdx.y * 32;
  const int ci = blockIdx.x * 32;
#pragma unroll
  for (int k = 0; k < 4; k++) {
    const int r = ri + ty + k * 8, c = ci + tx;
    tile[ty + k * 8][tx] = (r < M && c < N) ? R[(long)r * N + c] : 0.f;
  }
  __syncthreads();
#pragma unroll
  for (int k = 0; k < 4; k++) {
    const int orow = ci + ty + k * 8;
    const int ocol = ri + tx;
    if (orow < Np && ocol < Mp) {
      const bool in = (orow < N && ocol < M);
      const float v = tile[tx][ty + k * 8];
      Qp[(long)orow * Mp + ocol] =
          in ? (signed char)__float2int_rn((v - 0.5f) * 254.f) : (signed char)0;
    }
  }
}

// ---------------------------------------------------------------------------
// Mirror lower triangle of fp32 S [n,n] into strict upper, 32x32 tile pairs.
// ---------------------------------------------------------------------------
__global__ __launch_bounds__(256) void mirror_kernel(float* __restrict__ S,
                                                     int n) {
  __shared__ float tile[32][33];
  int by, bx;
  tri_decode(blockIdx.x, by, bx);
  const int tj = by + 1, ti = bx;  // tj > ti
  const int sr = tj * 32, sc = ti * 32;
  const int tx = threadIdx.x & 31;
  const int ty = threadIdx.x >> 5;
#pragma unroll
  for (int k = 0; k < 4; k++) {
    const int r = sr + ty + k * 8, c = sc + tx;
    tile[ty + k * 8][tx] = (r < n && c < n) ? S[(long)r * n + c] : 0.f;
  }
  __syncthreads();
#pragma unroll
  for (int k = 0; k < 4; k++) {
    const int r = sc + ty + k * 8, c = sr + tx;
    if (r < n && c < n) S[(long)r * n + c] = tile[tx][ty + k * 8];
  }
}

// ---------------------------------------------------------------------------
// norms + plain sums
// ---------------------------------------------------------------------------
__global__ __launch_bounds__(256) void row_norm_sum(
    const float* __restrict__ R, float* __restrict__ inv_n,
    float* __restrict__ sv, int M, int K) {
  __shared__ float redA[256];
  __shared__ float redB[256];
  const int row = blockIdx.x;
  float s2 = 0.f, s1 = 0.f;
  for (int j = threadIdx.x; j < K; j += 256) {
    const float v = R[(long)row * K + j];
    s2 = fmaf(v, v, s2);
    s1 += v;
  }
  redA[threadIdx.x] = s2;
  redB[threadIdx.x] = s1;
  __syncthreads();
  for (int o = 128; o > 0; o >>= 1) {
    if (threadIdx.x < o) {
      redA[threadIdx.x] += redA[threadIdx.x + o];
      redB[threadIdx.x] += redB[threadIdx.x + o];
    }
    __syncthreads();
  }
  if (threadIdx.x == 0) {
    inv_n[row] = 1.f / (sqrtf(redA[0]) + EPS);
    sv[row] = redB[0];
  }
}

// Column sums-of-squares + plain column sums, two-phase (coalesced).
__global__ __launch_bounds__(256) void col_sums_kernel(
    const float* __restrict__ R, float* __restrict__ acc2,
    float* __restrict__ acc1, int M, int N, int rows_per_chunk) {
  const int j = blockIdx.x * 256 + threadIdx.x;
  if (j >= N) return;
  const int r0 = blockIdx.y * rows_per_chunk;
  const int r1 = min(M, r0 + rows_per_chunk);
  float s2 = 0.f, s1 = 0.f;
  for (int i = r0; i < r1; i++) {
    const float v = R[(long)i * N + j];
    s2 = fmaf(v, v, s2);
    s1 += v;
  }
  atomicAdd(&acc2[j], s2);
  atomicAdd(&acc1[j], s1);
}

// inv_n[i] = 1/(sqrt(acc[i]) + EPS)
__global__ __launch_bounds__(256) void inv_norm_finalize(
    const float* __restrict__ acc, float* __restrict__ inv_n, int n) {
  const int i = blockIdx.x * 256 + threadIdx.x;
  if (i < n) inv_n[i] = 1.f / (sqrtf(acc[i]) + EPS);
}

// ---------------------------------------------------------------------------
// Top-k, one wave64 per row, ZERO LDS (verified round 6).
// ---------------------------------------------------------------------------
__global__ __launch_bounds__(64) void topk_kernel(
    float* __restrict__ G, const float* __restrict__ inv_n,
    __bf16* __restrict__ adj, float* __restrict__ rowsum,
    float* __restrict__ colsum, int n, int np, const int* __restrict__ kptr) {
  const int row = blockIdx.x;
  const int lane = threadIdx.x;
  const int k = *kptr;
  const float invr = inv_n[row];

  float v0 = -INFINITY, v1 = -INFINITY, v2 = -INFINITY, v3 = -INFINITY;
  int i0 = n, i1 = n, i2 = n, i3 = n;

  for (int j = lane; j < n; j += 64) {
    const float v =
        (j == row) ? -INFINITY : G[(long)row * n + j] * invr * inv_n[j];
    if (v > v3) {
      if (v > v1) {
        if (v > v0) {
          v3 = v2; i3 = i2; v2 = v1; i2 = i1; v1 = v0; i1 = i0; v0 = v; i0 = j;
        } else {
          v3 = v2; i3 = i2; v2 = v1; i2 = i1; v1 = v; i1 = j;
        }
      } else {
        if (v > v2) {
          v3 = v2; i3 = i2; v2 = v; i2 = j;
        } else {
          v3 = v; i3 = j;
        }
      }
    }
  }

  float rsum = 0.f;
  for (int t = 0; t < k; t++) {
    float v = v0;
    int i = i0;
#pragma unroll
    for (int off = 32; off > 0; off >>= 1) {
      const float ov = __shfl_xor(v, off);
      const int oi = __shfl_xor(i, off);
      if (ov > v || (ov == v && oi < i)) { v = ov; i = oi; }
    }
    if (lane == 0) {
      adj[(long)row * np + i] = (__bf16)v;
      atomicAdd(&colsum[i], v);
      rsum += v;
    }
    if ((i & 63) == lane) {
      G[(long)row * n + i] = -INFINITY;  // mark removed (my slice)
      v0 = v1; i0 = i1; v1 = v2; i1 = i2; v2 = v3; i2 = i3;
      v3 = -INFINITY; i3 = n;
      if (i0 == n) {  // list exhausted -> rare rescan of my slice
        for (int j = lane; j < n; j += 64) {
          const float vv =
              (j == row) ? -INFINITY : G[(long)row * n + j] * invr * inv_n[j];
          if (vv > v3) {
            if (vv > v1) {
              if (vv > v0) {
                v3 = v2; i3 = i2; v2 = v1; i2 = i1; v1 = v0; i1 = i0;
                v0 = vv; i0 = j;
              } else {
                v3 = v2; i3 = i2; v2 = v1; i2 = i1; v1 = vv; i1 = j;
              }
            } else {
              if (vv > v2) {
                v3 = v2; i3 = i2; v2 = vv; i2 = j;
              } else {
                v3 = vv; i3 = j;
              }
            }
          }
        }
      }
    }
  }
  if (lane == 0) rowsum[row] = rsum;
}

// f[i] = 1/sqrt(0.5*(rowsum+colsum) + EPS)
__global__ __launch_bounds__(256) void finalize_kernel(
    const float* __restrict__ rs, const float* __restrict__ cs,
    float* __restrict__ f, int n) {
  const int i = blockIdx.x * 256 + threadIdx.x;
  if (i < n) f[i] = rsqrtf(0.5f * (rs[i] + cs[i]) + EPS);
}

// in-place: adj[i,j] = adj[j,i] = 0.5*(adj[i,j]+adj[j,i]) * f[i]*f[j]
// 2D grid (i = blockIdx.y).
__global__ __launch_bounds__(256) void symscale_kernel(
    __bf16* __restrict__ adj, const float* __restrict__ f, int n, int np) {
  const int i = blockIdx.y;
  const int j = blockIdx.x * 256 + threadIdx.x;
  if (j >= np || j <= i || i >= n || j >= n) return;
  const float a = (float)adj[(long)i * np + j];
  const float b = (float)adj[(long)j * np + i];
  const float m = 0.5f * (a + b) * f[i] * f[j];
  adj[(long)i * np + j] = (__bf16)m;
  adj[(long)j * np + i] = (__bf16)m;
}

// ---------------------------------------------------------------------------
extern "C" void kernel_launch(void* const* d_in, const int* in_sizes, int n_in,
                              void* d_out, int out_size, void* d_ws,
                              size_t ws_size, hipStream_t stream) {
  const float* R = (const float*)d_in[0];
  const int* k_users_p = (const int*)d_in[1];
  const int* k_items_p = (const int*)d_in[2];
  float* out = (float*)d_out;
  const int NU = N_USERS, NI = N_ITEMS;

  // ---- workspace layout (peak 328.4 MB; Rh deleted, IhT relocated) ----
  // IhT   [ 1.0,  25.7)  transpose -> sparse prop1  (exclusive region)
  // cmpL  [26.0,  29.2)  compact -> sparse prop1
  // cmpC  [29.5,  29.6)  compact -> sparse prop1
  // cmpR  [29.7,  29.8)  compact -> sparse prop1
  // Uh    [51.0,  75.7)  pad_quant -> user gram
  // Su    [77.0, 221.0)  user gram -> user topk
  // Si    [128., 192.0)  item gram -> item topk   (inside future-Su, ok)
  // adjIb [222., 255.6)  item topk -> compact
  // adjUb [256., 328.4)  user topk -> prop2
  // Tt    [77.0, 126.3)  sparse prop1 -> prop2    (over dead Su)
  char* ws = (char*)d_ws;
  float* invNu = (float*)(ws + 0);        // 24 KB
  float* invNi = (float*)(ws + 32768);    // 16 KB
  float* rsU = (float*)(ws + 65536);      // 24 KB
  float* csU = (float*)(ws + 98304);      // 24 KB
  float* rsI = (float*)(ws + 131072);     // 16 KB
  float* csI = (float*)(ws + 163840);     // 16 KB
  float* fU = (float*)(ws + 196608);      // 24 KB
  float* fI = (float*)(ws + 229376);      // 16 KB
  float* nrmI = (float*)(ws + 262144);    // 16 KB (col sumsq accumulator)
  float* svU = (float*)(ws + 294912);     // 24 KB (row sums of R)
  float* svI = (float*)(ws + 327680);     // 16 KB (col sums of R)
  const long MB = 1000000L;
  signed char* IhT = (signed char*)(ws + 1 * MB);
  unsigned int* cmpL = (unsigned int*)(ws + 26 * MB);  // 4096*192*4 = 3.15 MB
  int* cmpC = (int*)(ws + 29500000L);                  // 16 KB
  float* cmpR = (float*)(ws + 29700000L);              // 16 KB
  signed char* Uh = (signed char*)(ws + 51 * MB);
  float* Su = (float*)(ws + 77 * MB);
  float* Si = (float*)(ws + 128 * MB);
  __bf16* adjIb = (__bf16*)(ws + 222 * MB);
  __bf16* adjUb = (__bf16*)(ws + 256 * MB);
  __bf16* Tt = (__bf16*)(ws + 77 * MB);

  // ---- norms + sums + quantized conversions ----
  row_norm_sum<<<NU, 256, 0, stream>>>(R, invNu, svU, NU, NI);
  hipMemsetAsync(nrmI, 0, NI * sizeof(float), stream);
  hipMemsetAsync(svI, 0, NI * sizeof(float), stream);
  col_sums_kernel<<<dim3((NI + 255) / 256, 60), 256, 0, stream>>>(R, nrmI, svI,
                                                                  NU, NI, 100);
  inv_norm_finalize<<<(NI + 255) / 256, 256, 0, stream>>>(nrmI, invNi, NI);
  pad_quant_kernel<<<dim3(NI_P / 256, NU_P), 256, 0, stream>>>(R, Uh, NU, NI,
                                                               NI_P);
  transpose_quant_kernel<<<dim3(NI_P / 32, NU_P / 32), 256, 0, stream>>>(
      R, IhT, NU, NI, NU_P, NI_P);

  // ================= item graph =================
  // S = G2/254^2 + 0.5*(svI[i]+svI[j]) - NU/4
  mfma_gram_i8<NU_P, NU_P, N_ITEMS><<<32 * 33 / 2, 256, 0, stream>>>(
      IhT, svI, Si, NI, -0.25f * (float)NU);
  {
    const int T = (NI + 31) / 32;  // 125
    mirror_kernel<<<T * (T - 1) / 2, 256, 0, stream>>>(Si, NI);
  }
  hipMemsetAsync(adjIb, 0, (long)NI_P * NI_P * sizeof(__bf16), stream);
  hipMemsetAsync(csI, 0, NI * sizeof(float), stream);
  topk_kernel<<<NI, 64, 0, stream>>>(Si, invNi, adjIb, rsI, csI, NI, NI_P,
                                     k_items_p);
  finalize_kernel<<<(NI + 255) / 256, 256, 0, stream>>>(rsI, csI, fI, NI);
  symscale_kernel<<<dim3((NI_P + 255) / 256, NI_P), 256, 0, stream>>>(
      adjIb, fI, NI, NI_P);
  // compact adjI into fixed-width lists for the sparse prop1
  compact_adj_kernel<<<NI, 256, 0, stream>>>(adjIb, cmpL, cmpC, cmpR, NI,
                                             NI_P);

  // ================= user graph =================
  mfma_gram_i8<NI_P, NI_P, N_USERS><<<47 * 48 / 2, 256, 0, stream>>>(
      Uh, svU, Su, NU, -0.25f * (float)NI);
  {
    const int T = (NU + 31) / 32;  // 188
    mirror_kernel<<<T * (T - 1) / 2, 256, 0, stream>>>(Su, NU);
  }
  hipMemsetAsync(adjUb, 0, (long)NU_P * NU_P * sizeof(__bf16), stream);
  hipMemsetAsync(csU, 0, NU * sizeof(float), stream);
  topk_kernel<<<NU, 64, 0, stream>>>(Su, invNu, adjUb, rsU, csU, NU, NU_P,
                                     k_users_p);
  finalize_kernel<<<(NU + 255) / 256, 256, 0, stream>>>(rsU, csU, fU, NU);
  symscale_kernel<<<dim3((NU_P + 255) / 256, NU_P), 256, 0, stream>>>(
      adjUb, fU, NU, NU_P);

  // ================= propagation =================
  // prop1 (sparse gather): Tt[i,:] = sum_j adjI[i,j] * R[:,j]
  hipMemsetAsync(Tt + (long)NI * NU_P, 0,
                 (long)(NI_P - NI) * NU_P * sizeof(__bf16), stream);
  spmm_prop1_kernel<<<NI, 256, 0, stream>>>(cmpL, cmpC, cmpR, IhT, Tt);
  // prop2 (dense, verified): out = adjU @ T = adjUb @ Tt^T
  mfma_prop_bf16<NU_P, NU_P, NU_P, N_ITEMS, 0><<<47 * 32, 256, 0, stream>>>(
      adjUb, Tt, out, nullptr, NU, NI, 47, 32);
}

// Round 12
// 1702.880 us; speedup vs baseline: 1.0253x; 1.0253x over previous
//
#include <hip/hip_runtime.h>
#include <math.h>

#define EPS 1e-8f

constexpr int N_USERS = 6000;
constexpr int N_ITEMS = 4000;
constexpr int NU_P = 6016;  // 47 * 128
constexpr int NI_P = 4096;  // 32 * 128

typedef __bf16 bf16_8 __attribute__((ext_vector_type(8)));
typedef float f32_4 __attribute__((ext_vector_type(4)));
typedef int i32x4 __attribute__((ext_vector_type(4)));

// ---------------------------------------------------------------------------
__device__ __forceinline__ void stage16(const void* g, void* l) {
  __builtin_amdgcn_global_load_lds(
      (const __attribute__((address_space(1))) void*)g,
      (__attribute__((address_space(3))) void*)l, 16, 0, 0);
}

// XCD-aware bijective swizzle (requires nwg % 8 == 0; all MFMA grids are).
__device__ __forceinline__ int xcd_swz(int p, int nwg) {
  return (p & 7) * (nwg >> 3) + (p >> 3);
}

// triangular decode: p -> (by, bx) with bx <= by
__device__ __forceinline__ void tri_decode(int p, int& by, int& bx) {
  int r = (int)((sqrtf(8.f * p + 1.f) - 1.f) * 0.5f);
  while ((r + 1) * (r + 2) / 2 <= p) r++;
  while (r * (r + 1) / 2 > p) r--;
  by = r;
  bx = p - r * (r + 1) / 2;
}

// grouped decode (G=8 rows, column-major within band) for L2 locality
__device__ __forceinline__ void grp_decode(int p, int nby, int nbx, int& by,
                                           int& bx) {
  const int G = 8;
  const int wide = G * nbx;
  const int band = p / wide;
  const int rem = p - band * wide;
  const int h = min(G, nby - band * G);
  by = band * G + rem % h;
  bx = rem / h;
}

// ---------------------------------------------------------------------------
// bf16 prop GEMM — ROUND-7/10 KERNEL VERBATIM (measured 376-381 us; the
// empirical optimum of the 128^2 structure: batch 8 stages -> one vmcnt drain
// per 64-K -> 32 MFMA. Interleaved prefetch variants (r8 runtime-idx, r9
// static-idx unrolled) both regressed; sparse prop1 (r11) was a wash).
// ---------------------------------------------------------------------------
template <int KK, int LDA, int LDB, int LDC, int OUTBF16>
__global__ __launch_bounds__(256) void mfma_prop_bf16(
    const __bf16* __restrict__ A, const __bf16* __restrict__ B,
    float* __restrict__ Cf, __bf16* __restrict__ Cb, int M, int N, int nby,
    int nbx) {
  __shared__ __bf16 sA[2][128 * 32];
  __shared__ __bf16 sB[2][128 * 32];

  int by, bx;
  grp_decode(xcd_swz(blockIdx.x, gridDim.x), nby, nbx, by, bx);

  const int tid = threadIdx.x;
  const int lane = tid & 63;
  const int wave = tid >> 6;
  const int wm = (wave >> 1) * 64;
  const int wn = (wave & 1) * 64;
  const int lm = lane & 15;
  const int kg = lane >> 4;
  const long row0 = (long)by * 128;
  const long col0 = (long)bx * 128;

  f32_4 acc[4][4];
#pragma unroll
  for (int i = 0; i < 4; i++)
#pragma unroll
    for (int j = 0; j < 4; j++) acc[i][j] = (f32_4){0.f, 0.f, 0.f, 0.f};

  const int c0 = tid, c1 = tid + 256;
  const int r0c = c0 >> 2, j0c = ((c0 & 3) - (r0c >> 1)) & 3;
  const int r1c = c1 >> 2, j1c = ((c1 & 3) - (r1c >> 1)) & 3;

  // loop-invariant fragment offsets (elements)
  int offA[4], offB[4];
#pragma unroll
  for (int i = 0; i < 4; i++) {
    const int ra = wm + i * 16 + lm;
    const int rb = wn + i * 16 + lm;
    offA[i] = (ra * 4 + ((kg + (ra >> 1)) & 3)) * 8;
    offB[i] = (rb * 4 + ((kg + (rb >> 1)) & 3)) * 8;
  }

  const __bf16* a0 = A + (row0 + r0c) * LDA + j0c * 8;
  const __bf16* a1 = A + (row0 + r1c) * LDA + j1c * 8;
  const __bf16* b0 = B + (col0 + r0c) * LDB + j0c * 8;
  const __bf16* b1 = B + (col0 + r1c) * LDB + j1c * 8;

  for (int k0 = 0; k0 < KK; k0 += 64) {
    stage16(a0 + k0, &sA[0][c0 * 8]);
    stage16(a1 + k0, &sA[0][c1 * 8]);
    stage16(b0 + k0, &sB[0][c0 * 8]);
    stage16(b1 + k0, &sB[0][c1 * 8]);
    stage16(a0 + k0 + 32, &sA[1][c0 * 8]);
    stage16(a1 + k0 + 32, &sA[1][c1 * 8]);
    stage16(b0 + k0 + 32, &sB[1][c0 * 8]);
    stage16(b1 + k0 + 32, &sB[1][c1 * 8]);
    __syncthreads();

#pragma unroll
    for (int h = 0; h < 2; h++) {
      bf16_8 a[4], b[4];
#pragma unroll
      for (int i = 0; i < 4; i++) {
        a[i] = *(const bf16_8*)&sA[h][offA[i]];
        b[i] = *(const bf16_8*)&sB[h][offB[i]];
      }
#pragma unroll
      for (int i = 0; i < 4; i++)
#pragma unroll
        for (int j = 0; j < 4; j++)
          acc[i][j] = __builtin_amdgcn_mfma_f32_16x16x32_bf16(a[i], b[j],
                                                              acc[i][j], 0, 0,
                                                              0);
    }
    __syncthreads();
  }

  // epilogue: C/D layout col=lane&15, row=(lane>>4)*4+reg
#pragma unroll
  for (int i = 0; i < 4; i++)
#pragma unroll
    for (int j = 0; j < 4; j++)
#pragma unroll
      for (int r = 0; r < 4; r++) {
        const long gm = row0 + wm + i * 16 + kg * 4 + r;
        const long gn = col0 + wn + j * 16 + lm;
        if (gm < M && gn < N) {
          if (OUTBF16)
            Cb[gm * LDC + gn] = (__bf16)acc[i][j][r];
          else
            Cf[gm * LDC + gn] = acc[i][j][r];
        }
      }
}

// ---------------------------------------------------------------------------
// Single-plane centered-i8 GRAM — ROUND-6/10 SCHEDULE (single 16 KB buffers,
// BK=64: stage 4 -> drain -> 16 MFMA -> barrier) + compile-time strides.
// Math verified r3/r6; kernel byte-identical to r10.
// ---------------------------------------------------------------------------
template <int KK, int LD, int LDC>
__global__ __launch_bounds__(256) void mfma_gram_i8(
    const signed char* __restrict__ Q, const float* __restrict__ sv,
    float* __restrict__ C, int Nn, float negq) {
  __shared__ signed char sA[128 * 64];
  __shared__ signed char sB[128 * 64];

  int by, bx;
  tri_decode(xcd_swz(blockIdx.x, gridDim.x), by, bx);

  const int tid = threadIdx.x;
  const int lane = tid & 63;
  const int wave = tid >> 6;
  const int wm = (wave >> 1) * 64;
  const int wn = (wave & 1) * 64;
  const int lm = lane & 15;
  const int kg = lane >> 4;
  const long row0 = (long)by * 128;
  const long col0 = (long)bx * 128;
  const float scale = 1.f / (254.f * 254.f);

  i32x4 acc[4][4];
#pragma unroll
  for (int i = 0; i < 4; i++)
#pragma unroll
    for (int j = 0; j < 4; j++) acc[i][j] = (i32x4){0, 0, 0, 0};

  const int c0 = tid, c1 = tid + 256;
  const int r0c = c0 >> 2, j0c = ((c0 & 3) - (r0c >> 1)) & 3;
  const int r1c = c1 >> 2, j1c = ((c1 & 3) - (r1c >> 1)) & 3;

  int offA[4], offB[4];
#pragma unroll
  for (int i = 0; i < 4; i++) {
    const int ra = wm + i * 16 + lm;
    const int rb = wn + i * 16 + lm;
    offA[i] = (ra * 4 + ((kg + (ra >> 1)) & 3)) * 16;
    offB[i] = (rb * 4 + ((kg + (rb >> 1)) & 3)) * 16;
  }

  const signed char* a0 = Q + (row0 + r0c) * LD + j0c * 16;
  const signed char* a1 = Q + (row0 + r1c) * LD + j1c * 16;
  const signed char* b0 = Q + (col0 + r0c) * LD + j0c * 16;
  const signed char* b1 = Q + (col0 + r1c) * LD + j1c * 16;

  for (int k0 = 0; k0 < KK; k0 += 64) {
    stage16(a0 + k0, &sA[c0 * 16]);
    stage16(a1 + k0, &sA[c1 * 16]);
    stage16(b0 + k0, &sB[c0 * 16]);
    stage16(b1 + k0, &sB[c1 * 16]);
    __syncthreads();

    i32x4 a[4], b[4];
#pragma unroll
    for (int i = 0; i < 4; i++) {
      a[i] = *(const i32x4*)&sA[offA[i]];
      b[i] = *(const i32x4*)&sB[offB[i]];
    }
#pragma unroll
    for (int i = 0; i < 4; i++)
#pragma unroll
      for (int j = 0; j < 4; j++)
        acc[i][j] = __builtin_amdgcn_mfma_i32_16x16x64_i8(a[i], b[j],
                                                          acc[i][j], 0, 0, 0);
    __syncthreads();
  }

#pragma unroll
  for (int i = 0; i < 4; i++)
#pragma unroll
    for (int j = 0; j < 4; j++)
#pragma unroll
      for (int r = 0; r < 4; r++) {
        const long gm = row0 + wm + i * 16 + kg * 4 + r;
        const long gn = col0 + wn + j * 16 + lm;
        if (gm < Nn && gn < Nn)
          C[gm * LDC + gn] = fmaf((float)acc[i][j][r], scale,
                                  0.5f * (sv[gm] + sv[gn]) + negq);
      }
}

// ---------------------------------------------------------------------------
// R [M,N] fp32 -> padded bf16 (for prop1) + centered-i8 plane (user gram)
// ---------------------------------------------------------------------------
__global__ __launch_bounds__(256) void pad_quant_kernel(
    const float* __restrict__ R, __bf16* __restrict__ H,
    signed char* __restrict__ Qp, int M, int N, int Np) {
  const int r = blockIdx.y;
  const int c = blockIdx.x * 256 + threadIdx.x;
  if (c >= Np) return;
  const bool in = (r < M && c < N);
  const float v = in ? R[(long)r * N + c] : 0.f;
  H[(long)r * Np + c] = (__bf16)v;
  Qp[(long)r * Np + c] =
      in ? (signed char)__float2int_rn((v - 0.5f) * 254.f) : (signed char)0;
}

// ---------------------------------------------------------------------------
// Transpose fp32 [M,N] -> padded centered-i8 [Np, Mp] (item gram), LDS-tiled.
// ---------------------------------------------------------------------------
__global__ __launch_bounds__(256) void transpose_quant_kernel(
    const float* __restrict__ R, signed char* __restrict__ Qp, int M, int N,
    int Mp, int Np) {
  __shared__ float tile[32][33];
  const int tx = threadIdx.x & 31;
  const int ty = threadIdx.x >> 5;
  const int ri = blockIdx.y * 32;
  const int ci = blockIdx.x * 32;
#pragma unroll
  for (int k = 0; k < 4; k++) {
    const int r = ri + ty + k * 8, c = ci + tx;
    tile[ty + k * 8][tx] = (r < M && c < N) ? R[(long)r * N + c] : 0.f;
  }
  __syncthreads();
#pragma unroll
  for (int k = 0; k < 4; k++) {
    const int orow = ci + ty + k * 8;
    const int ocol = ri + tx;
    if (orow < Np && ocol < Mp) {
      const bool in = (orow < N && ocol < M);
      const float v = tile[tx][ty + k * 8];
      Qp[(long)orow * Mp + ocol] =
          in ? (signed char)__float2int_rn((v - 0.5f) * 254.f) : (signed char)0;
    }
  }
}

// ---------------------------------------------------------------------------
// Mirror lower triangle of fp32 S [n,n] into strict upper, 32x32 tile pairs.
// ---------------------------------------------------------------------------
__global__ __launch_bounds__(256) void mirror_kernel(float* __restrict__ S,
                                                     int n) {
  __shared__ float tile[32][33];
  int by, bx;
  tri_decode(blockIdx.x, by, bx);
  const int tj = by + 1, ti = bx;  // tj > ti
  const int sr = tj * 32, sc = ti * 32;
  const int tx = threadIdx.x & 31;
  const int ty = threadIdx.x >> 5;
#pragma unroll
  for (int k = 0; k < 4; k++) {
    const int r = sr + ty + k * 8, c = sc + tx;
    tile[ty + k * 8][tx] = (r < n && c < n) ? S[(long)r * n + c] : 0.f;
  }
  __syncthreads();
#pragma unroll
  for (int k = 0; k < 4; k++) {
    const int r = sc + ty + k * 8, c = sr + tx;
    if (r < n && c < n) S[(long)r * n + c] = tile[tx][ty + k * 8];
  }
}

// ---------------------------------------------------------------------------
// norms + plain sums
// ---------------------------------------------------------------------------
__global__ __launch_bounds__(256) void row_norm_sum(
    const float* __restrict__ R, float* __restrict__ inv_n,
    float* __restrict__ sv, int M, int K) {
  __shared__ float redA[256];
  __shared__ float redB[256];
  const int row = blockIdx.x;
  float s2 = 0.f, s1 = 0.f;
  for (int j = threadIdx.x; j < K; j += 256) {
    const float v = R[(long)row * K + j];
    s2 = fmaf(v, v, s2);
    s1 += v;
  }
  redA[threadIdx.x] = s2;
  redB[threadIdx.x] = s1;
  __syncthreads();
  for (int o = 128; o > 0; o >>= 1) {
    if (threadIdx.x < o) {
      redA[threadIdx.x] += redA[threadIdx.x + o];
      redB[threadIdx.x] += redB[threadIdx.x + o];
    }
    __syncthreads();
  }
  if (threadIdx.x == 0) {
    inv_n[row] = 1.f / (sqrtf(redA[0]) + EPS);
    sv[row] = redB[0];
  }
}

// Column sums-of-squares + plain column sums, two-phase (coalesced).
__global__ __launch_bounds__(256) void col_sums_kernel(
    const float* __restrict__ R, float* __restrict__ acc2,
    float* __restrict__ acc1, int M, int N, int rows_per_chunk) {
  const int j = blockIdx.x * 256 + threadIdx.x;
  if (j >= N) return;
  const int r0 = blockIdx.y * rows_per_chunk;
  const int r1 = min(M, r0 + rows_per_chunk);
  float s2 = 0.f, s1 = 0.f;
  for (int i = r0; i < r1; i++) {
    const float v = R[(long)i * N + j];
    s2 = fmaf(v, v, s2);
    s1 += v;
  }
  atomicAdd(&acc2[j], s2);
  atomicAdd(&acc1[j], s1);
}

// inv_n[i] = 1/(sqrt(acc[i]) + EPS)
__global__ __launch_bounds__(256) void inv_norm_finalize(
    const float* __restrict__ acc, float* __restrict__ inv_n, int n) {
  const int i = blockIdx.x * 256 + threadIdx.x;
  if (i < n) inv_n[i] = 1.f / (sqrtf(acc[i]) + EPS);
}

// ---------------------------------------------------------------------------
// Top-k, one wave64 per row, ZERO LDS (verified round 6). NEW: the block
// zeroes its OWN padded adj row first (8B stores, overlapped with nothing
// downstream until the barrier) — replaces the two large adj memset
// dispatches. __syncthreads() orders the zero-stores (all lanes) before the
// scatter-stores (lane 0); pad ROWS (>= n) are zeroed by a tiny host-side
// memset since no block visits them.
// ---------------------------------------------------------------------------
__global__ __launch_bounds__(64) void topk_kernel(
    float* __restrict__ G, const float* __restrict__ inv_n,
    __bf16* __restrict__ adj, float* __restrict__ rowsum,
    float* __restrict__ colsum, int n, int np, const int* __restrict__ kptr) {
  const int row = blockIdx.x;
  const int lane = threadIdx.x;
  const int k = *kptr;
  const float invr = inv_n[row];

  // zero my adjacency row (np % 4 == 0; row base is 8B-aligned)
  {
    unsigned long long* rowp =
        (unsigned long long*)(adj + (long)row * np);
    const int nq = np >> 2;  // 8B quads
    for (int q = lane; q < nq; q += 64) rowp[q] = 0ull;
  }

  float v0 = -INFINITY, v1 = -INFINITY, v2 = -INFINITY, v3 = -INFINITY;
  int i0 = n, i1 = n, i2 = n, i3 = n;

  for (int j = lane; j < n; j += 64) {
    const float v =
        (j == row) ? -INFINITY : G[(long)row * n + j] * invr * inv_n[j];
    if (v > v3) {
      if (v > v1) {
        if (v > v0) {
          v3 = v2; i3 = i2; v2 = v1; i2 = i1; v1 = v0; i1 = i0; v0 = v; i0 = j;
        } else {
          v3 = v2; i3 = i2; v2 = v1; i2 = i1; v1 = v; i1 = j;
        }
      } else {
        if (v > v2) {
          v3 = v2; i3 = i2; v2 = v; i2 = j;
        } else {
          v3 = v; i3 = j;
        }
      }
    }
  }

  __syncthreads();  // zero-stores visible before lane-0 scatter below

  float rsum = 0.f;
  for (int t = 0; t < k; t++) {
    float v = v0;
    int i = i0;
#pragma unroll
    for (int off = 32; off > 0; off >>= 1) {
      const float ov = __shfl_xor(v, off);
      const int oi = __shfl_xor(i, off);
      if (ov > v || (ov == v && oi < i)) { v = ov; i = oi; }
    }
    if (lane == 0) {
      adj[(long)row * np + i] = (__bf16)v;
      atomicAdd(&colsum[i], v);
      rsum += v;
    }
    if ((i & 63) == lane) {
      G[(long)row * n + i] = -INFINITY;  // mark removed (my slice)
      v0 = v1; i0 = i1; v1 = v2; i1 = i2; v2 = v3; i2 = i3;
      v3 = -INFINITY; i3 = n;
      if (i0 == n) {  // list exhausted -> rare rescan of my slice
        for (int j = lane; j < n; j += 64) {
          const float vv =
              (j == row) ? -INFINITY : G[(long)row * n + j] * invr * inv_n[j];
          if (vv > v3) {
            if (vv > v1) {
              if (vv > v0) {
                v3 = v2; i3 = i2; v2 = v1; i2 = i1; v1 = v0; i1 = i0;
                v0 = vv; i0 = j;
              } else {
                v3 = v2; i3 = i2; v2 = v1; i2 = i1; v1 = vv; i1 = j;
              }
            } else {
              if (vv > v2) {
                v3 = v2; i3 = i2; v2 = vv; i2 = j;
              } else {
                v3 = vv; i3 = j;
              }
            }
          }
        }
      }
    }
  }
  if (lane == 0) rowsum[row] = rsum;
}

// f[i] = 1/sqrt(0.5*(rowsum+colsum) + EPS)
__global__ __launch_bounds__(256) void finalize_kernel(
    const float* __restrict__ rs, const float* __restrict__ cs,
    float* __restrict__ f, int n) {
  const int i = blockIdx.x * 256 + threadIdx.x;
  if (i < n) f[i] = rsqrtf(0.5f * (rs[i] + cs[i]) + EPS);
}

// in-place: adj[i,j] = adj[j,i] = 0.5*(adj[i,j]+adj[j,i]) * f[i]*f[j]
// 2D grid (i = blockIdx.y): same per-element arithmetic as the verified
// linear version, without the 64-bit div/mod per thread.
__global__ __launch_bounds__(256) void symscale_kernel(
    __bf16* __restrict__ adj, const float* __restrict__ f, int n, int np) {
  const int i = blockIdx.y;
  const int j = blockIdx.x * 256 + threadIdx.x;
  if (j >= np || j <= i || i >= n || j >= n) return;
  const float a = (float)adj[(long)i * np + j];
  const float b = (float)adj[(long)j * np + i];
  const float m = 0.5f * (a + b) * f[i] * f[j];
  adj[(long)i * np + j] = (__bf16)m;
  adj[(long)j * np + i] = (__bf16)m;
}

// ---------------------------------------------------------------------------
extern "C" void kernel_launch(void* const* d_in, const int* in_sizes, int n_in,
                              void* d_out, int out_size, void* d_ws,
                              size_t ws_size, hipStream_t stream) {
  const float* R = (const float*)d_in[0];
  const int* k_users_p = (const int*)d_in[1];
  const int* k_items_p = (const int*)d_in[2];
  float* out = (float*)d_out;
  const int NU = N_USERS, NI = N_ITEMS;

  // ---- workspace layout (round-3/6/7/10 verified; peak 328.4 MB) ----
  // Rh    [ 1.0,  50.3)  pad_quant -> prop1
  // Uh    [51.0,  75.7)  pad_quant -> user gram
  // Su    [77.0, 221.0)  user gram -> user topk   (written AFTER IhT/Si die)
  // IhT   [103., 127.7)  transpose -> item gram   (inside future-Su, ok)
  // Si    [128., 192.0)  item gram -> item topk   (inside future-Su, ok)
  // adjIb [222., 255.6)  item topk -> prop1
  // adjUb [256., 328.4)  user topk -> prop2
  // Tt    [77.0, 126.3)  prop1 -> prop2           (over dead Su)
  char* ws = (char*)d_ws;
  float* invNu = (float*)(ws + 0);        // 24 KB
  float* invNi = (float*)(ws + 32768);    // 16 KB
  float* rsU = (float*)(ws + 65536);      // 24 KB
  float* csU = (float*)(ws + 98304);      // 24 KB
  float* rsI = (float*)(ws + 131072);     // 16 KB
  float* csI = (float*)(ws + 163840);     // 16 KB
  float* fU = (float*)(ws + 196608);      // 24 KB
  float* fI = (float*)(ws + 229376);      // 16 KB
  float* nrmI = (float*)(ws + 262144);    // 16 KB (col sumsq accumulator)
  float* svU = (float*)(ws + 294912);     // 24 KB (row sums of R)
  float* svI = (float*)(ws + 327680);     // 16 KB (col sums of R)
  const long MB = 1000000L;
  __bf16* Rh = (__bf16*)(ws + 1 * MB);
  signed char* Uh = (signed char*)(ws + 51 * MB);
  float* Su = (float*)(ws + 77 * MB);
  signed char* IhT = (signed char*)(ws + 103 * MB);
  float* Si = (float*)(ws + 128 * MB);
  __bf16* adjIb = (__bf16*)(ws + 222 * MB);
  __bf16* adjUb = (__bf16*)(ws + 256 * MB);
  __bf16* Tt = (__bf16*)(ws + 77 * MB);

  // ---- norms + sums + quantized conversions ----
  row_norm_sum<<<NU, 256, 0, stream>>>(R, invNu, svU, NU, NI);
  hipMemsetAsync(nrmI, 0, NI * sizeof(float), stream);
  hipMemsetAsync(svI, 0, NI * sizeof(float), stream);
  col_sums_kernel<<<dim3((NI + 255) / 256, 60), 256, 0, stream>>>(R, nrmI, svI,
                                                                  NU, NI, 100);
  inv_norm_finalize<<<(NI + 255) / 256, 256, 0, stream>>>(nrmI, invNi, NI);
  pad_quant_kernel<<<dim3(NI_P / 256, NU_P), 256, 0, stream>>>(R, Rh, Uh, NU,
                                                               NI, NI_P);
  transpose_quant_kernel<<<dim3(NI_P / 32, NU_P / 32), 256, 0, stream>>>(
      R, IhT, NU, NI, NU_P, NI_P);

  // ================= item graph =================
  // S = G2/254^2 + 0.5*(svI[i]+svI[j]) - NU/4
  mfma_gram_i8<NU_P, NU_P, N_ITEMS><<<32 * 33 / 2, 256, 0, stream>>>(
      IhT, svI, Si, NI, -0.25f * (float)NU);
  {
    const int T = (NI + 31) / 32;  // 125
    mirror_kernel<<<T * (T - 1) / 2, 256, 0, stream>>>(Si, NI);
  }
  // pad rows of adjI (rows NI..NI_P-1) are never visited by topk -> memset
  hipMemsetAsync(adjIb + (long)NI * NI_P, 0,
                 (long)(NI_P - NI) * NI_P * sizeof(__bf16), stream);
  hipMemsetAsync(csI, 0, NI * sizeof(float), stream);
  topk_kernel<<<NI, 64, 0, stream>>>(Si, invNi, adjIb, rsI, csI, NI, NI_P,
                                     k_items_p);
  finalize_kernel<<<(NI + 255) / 256, 256, 0, stream>>>(rsI, csI, fI, NI);
  symscale_kernel<<<dim3((NI_P + 255) / 256, NI_P), 256, 0, stream>>>(
      adjIb, fI, NI, NI_P);

  // ================= user graph =================
  mfma_gram_i8<NI_P, NI_P, N_USERS><<<47 * 48 / 2, 256, 0, stream>>>(
      Uh, svU, Su, NU, -0.25f * (float)NI);
  {
    const int T = (NU + 31) / 32;  // 188
    mirror_kernel<<<T * (T - 1) / 2, 256, 0, stream>>>(Su, NU);
  }
  hipMemsetAsync(adjUb + (long)NU * NU_P, 0,
                 (long)(NU_P - NU) * NU_P * sizeof(__bf16), stream);
  hipMemsetAsync(csU, 0, NU * sizeof(float), stream);
  topk_kernel<<<NU, 64, 0, stream>>>(Su, invNu, adjUb, rsU, csU, NU, NU_P,
                                     k_users_p);
  finalize_kernel<<<(NU + 255) / 256, 256, 0, stream>>>(rsU, csU, fU, NU);
  symscale_kernel<<<dim3((NU_P + 255) / 256, NU_P), 256, 0, stream>>>(
      adjUb, fU, NU, NU_P);

  // ================= propagation (bf16, verified) =================
  // prop1: Tt = T^T = adjI @ R^T  (bf16 out, full padded, over dead Su space)
  mfma_prop_bf16<NI_P, NI_P, NI_P, NU_P, 1><<<32 * 47, 256, 0, stream>>>(
      adjIb, Rh, nullptr, Tt, NI_P, NU_P, 32, 47);
  // prop2: out = adjU @ T = adjUb @ Tt^T
  mfma_prop_bf16<NU_P, NU_P, NU_P, N_ITEMS, 0><<<47 * 32, 256, 0, stream>>>(
      adjUb, Tt, out, nullptr, NU, NI, 47, 32);
}